// Round 2
// baseline (3928.531 us; speedup 1.0000x reference)
//
#include <hip/hip_runtime.h>

#define Hd 128
#define Tn 1024
#define Dn 5
#define Ln 16
#define Bn 512

__device__ __forceinline__ float sigm(float x) { return 1.0f / (1.0f + __expf(-x)); }
__device__ __forceinline__ float tanh_fast(float x) { return 1.0f - 2.0f / (1.0f + __expf(2.0f * x)); }

// Persistent GRU autoencoder kernel.
// grid = 256 WGs (1/CU), block = 256 threads (4 waves = 1 wave/SIMD).
// Each WG owns batch rows {2*wg, 2*wg+1}. Thread (bl, j) owns hidden index j of
// batch row bl: W_hh rows {j (r), 128+j (z), 256+j (n)} live in 384 VGPRs.
// Encoder: h ping-pong in LDS, broadcast ds_read_b128, 1 barrier/step,
//          x[t+1] software-prefetched into regs (hides global latency).
// Decoder: h history kept in a 32-deep LDS tile (slot s&31); recon projection
//          done in bulk every 32 steps (coalesced stores), not per-step shfl.
__global__ __launch_bounds__(256, 1) void gru_ae_kernel(
    const float* __restrict__ x,
    const float* __restrict__ eWih, const float* __restrict__ eWhh,
    const float* __restrict__ ebih, const float* __restrict__ ebhh,
    const float* __restrict__ efcW, const float* __restrict__ efcb,
    const float* __restrict__ dfcW, const float* __restrict__ dfcb,
    const float* __restrict__ dWih, const float* __restrict__ dWhh,
    const float* __restrict__ dbih, const float* __restrict__ dbhh,
    const float* __restrict__ oW, const float* __restrict__ ob,
    float* __restrict__ out)
{
    __shared__ float4 hbuf[2][2][Hd / 4];   // encoder ping-pong hidden state
    __shared__ float hs[2][32][Hd];         // decoder 32-step h history tile
    __shared__ float4 hdi4[2][Hd / 4];      // decoder input-hidden (h_dec_in)
    __shared__ float zl[2][Ln];             // latent z

    const int tid = threadIdx.x;
    const int bl = tid >> 7;        // 0..1 : local batch row
    const int j = tid & 127;        // 0..127 : hidden index
    const int b = blockIdx.x * 2 + bl;

    // ---- register-resident W_hh rows (encoder first) ----
    float4 wr[32], wz[32], wn[32];
    {
        const float4* p0 = (const float4*)(eWhh + (size_t)j * Hd);
        const float4* p1 = (const float4*)(eWhh + (size_t)(Hd + j) * Hd);
        const float4* p2 = (const float4*)(eWhh + (size_t)(2 * Hd + j) * Hd);
#pragma unroll
        for (int k = 0; k < 32; ++k) { wr[k] = p0[k]; wz[k] = p1[k]; wn[k] = p2[k]; }
    }
    // input-projection weight rows (D=5 each) + biases
    float wir[5], wiz[5], win[5];
#pragma unroll
    for (int d = 0; d < 5; ++d) {
        wir[d] = eWih[(size_t)j * Dn + d];
        wiz[d] = eWih[(size_t)(Hd + j) * Dn + d];
        win[d] = eWih[(size_t)(2 * Hd + j) * Dn + d];
    }
    float bihr = ebih[j], bihz = ebih[Hd + j], bihn = ebih[2 * Hd + j];
    float bhhr = ebhh[j], bhhz = ebhh[Hd + j], bhhn = ebhh[2 * Hd + j];

    // zero encoder h
    if (j < 32) {
        hbuf[0][bl][j] = make_float4(0.f, 0.f, 0.f, 0.f);
        hbuf[1][bl][j] = make_float4(0.f, 0.f, 0.f, 0.f);
    }
    __syncthreads();

    float h_self = 0.0f;
    int p = 0;
    const float* xrow = x + (size_t)b * Tn * Dn;

    // x[0] preload
    float xc0 = xrow[0], xc1 = xrow[1], xc2 = xrow[2], xc3 = xrow[3], xc4 = xrow[4];

    // ================= encoder: 1024 steps =================
#pragma unroll 1
    for (int t = 0; t < Tn; ++t) {
        // prefetch x[t+1] (independent of everything below; hides under FMAs)
        const int tn = (t + 1 < Tn) ? (t + 1) : t;
        const float* xtn = xrow + tn * Dn;
        float nx0 = xtn[0], nx1 = xtn[1], nx2 = xtn[2], nx3 = xtn[3], nx4 = xtn[4];

        float xpr = bihr + wir[0] * xc0 + wir[1] * xc1 + wir[2] * xc2 + wir[3] * xc3 + wir[4] * xc4;
        float xpz = bihz + wiz[0] * xc0 + wiz[1] * xc1 + wiz[2] * xc2 + wiz[3] * xc3 + wiz[4] * xc4;
        float xpn = bihn + win[0] * xc0 + win[1] * xc1 + win[2] * xc2 + win[3] * xc3 + win[4] * xc4;

        const float4* hv = hbuf[p][bl];
        float ar0 = 0.f, ar1 = 0.f, az0 = 0.f, az1 = 0.f, an0 = 0.f, an1 = 0.f;
#pragma unroll
        for (int k = 0; k < 32; ++k) {
            float4 h4 = hv[k];
            ar0 = fmaf(wr[k].x, h4.x, ar0); ar1 = fmaf(wr[k].y, h4.y, ar1);
            az0 = fmaf(wz[k].x, h4.x, az0); az1 = fmaf(wz[k].y, h4.y, az1);
            an0 = fmaf(wn[k].x, h4.x, an0); an1 = fmaf(wn[k].y, h4.y, an1);
            ar0 = fmaf(wr[k].z, h4.z, ar0); ar1 = fmaf(wr[k].w, h4.w, ar1);
            az0 = fmaf(wz[k].z, h4.z, az0); az1 = fmaf(wz[k].w, h4.w, az1);
            an0 = fmaf(wn[k].z, h4.z, an0); an1 = fmaf(wn[k].w, h4.w, an1);
        }
        float r = sigm(xpr + (ar0 + ar1) + bhhr);
        float zg = sigm(xpz + (az0 + az1) + bhhz);
        float n = tanh_fast(xpn + r * ((an0 + an1) + bhhn));
        float hnew = fmaf(zg, h_self - n, n);  // (1-z)*n + z*h
        h_self = hnew;
        ((float*)hbuf[p ^ 1][bl])[j] = hnew;
        xc0 = nx0; xc1 = nx1; xc2 = nx2; xc3 = nx3; xc4 = nx4;
        __syncthreads();
        p ^= 1;
    }
    // h_n now in hbuf[p] (p==0 after 1024 flips)

    // ================= latent z =================
    if (j < Ln) {
        const float4* wp = (const float4*)(efcW + (size_t)j * Hd);
        const float4* hv = hbuf[p][bl];
        float acc = efcb[j];
#pragma unroll
        for (int k = 0; k < 32; ++k) {
            float4 w4 = wp[k]; float4 h4 = hv[k];
            acc = fmaf(w4.x, h4.x, fmaf(w4.y, h4.y, fmaf(w4.z, h4.z, fmaf(w4.w, h4.w, acc))));
        }
        out[(size_t)Bn * Tn * Dn + (size_t)b * Ln + j] = acc;
        zl[bl][j] = acc;
    }
    __syncthreads();

    // ================= h_dec_in = z @ dec_fc_W.T + dec_fc_b =================
    {
        float acc = dfcb[j];
        const float4* wp = (const float4*)(dfcW + (size_t)j * Ln);
#pragma unroll
        for (int l4 = 0; l4 < 4; ++l4) {
            float4 w4 = wp[l4];
            acc = fmaf(w4.x, zl[bl][l4 * 4 + 0], acc);
            acc = fmaf(w4.y, zl[bl][l4 * 4 + 1], acc);
            acc = fmaf(w4.z, zl[bl][l4 * 4 + 2], acc);
            acc = fmaf(w4.w, zl[bl][l4 * 4 + 3], acc);
        }
        ((float*)hdi4[bl])[j] = acc;
    }
    __syncthreads();

    // ================= xp_dec = h_dec_in @ dec_W_ih.T + dec_b_ih =================
    float xdr, xdz, xdn;
    {
        const float4* p0 = (const float4*)(dWih + (size_t)j * Hd);
        const float4* p1 = (const float4*)(dWih + (size_t)(Hd + j) * Hd);
        const float4* p2 = (const float4*)(dWih + (size_t)(2 * Hd + j) * Hd);
#pragma unroll
        for (int k = 0; k < 32; ++k) { wr[k] = p0[k]; wz[k] = p1[k]; wn[k] = p2[k]; }
        float a0 = dbih[j], a1 = dbih[Hd + j], a2 = dbih[2 * Hd + j];
        const float4* hv = hdi4[bl];
#pragma unroll
        for (int k = 0; k < 32; ++k) {
            float4 h4 = hv[k];
            a0 = fmaf(wr[k].x, h4.x, fmaf(wr[k].y, h4.y, fmaf(wr[k].z, h4.z, fmaf(wr[k].w, h4.w, a0))));
            a1 = fmaf(wz[k].x, h4.x, fmaf(wz[k].y, h4.y, fmaf(wz[k].z, h4.z, fmaf(wz[k].w, h4.w, a1))));
            a2 = fmaf(wn[k].x, h4.x, fmaf(wn[k].y, h4.y, fmaf(wn[k].z, h4.z, fmaf(wn[k].w, h4.w, a2))));
        }
        xdr = a0; xdz = a1; xdn = a2;
    }

    // ---- decoder recurrent weights into registers ----
    {
        const float4* p0 = (const float4*)(dWhh + (size_t)j * Hd);
        const float4* p1 = (const float4*)(dWhh + (size_t)(Hd + j) * Hd);
        const float4* p2 = (const float4*)(dWhh + (size_t)(2 * Hd + j) * Hd);
#pragma unroll
        for (int k = 0; k < 32; ++k) { wr[k] = p0[k]; wz[k] = p1[k]; wn[k] = p2[k]; }
    }
    bhhr = dbhh[j]; bhhz = dbhh[Hd + j]; bhhn = dbhh[2 * Hd + j];

    // zero the "previous h" slot for decoder step 0 (slot 31)
    hs[bl][31][j] = 0.0f;
    h_self = 0.0f;
    __syncthreads();

    // ================= decoder: 1024 steps in 32-step tiles =================
#pragma unroll 1
    for (int s0 = 0; s0 < Tn; s0 += 32) {
#pragma unroll 1
        for (int ss = 0; ss < 32; ++ss) {
            const int ip = (ss + 31) & 31;   // previous-h slot
            const float4* hv = (const float4*)hs[bl][ip];
            float ar0 = 0.f, ar1 = 0.f, az0 = 0.f, az1 = 0.f, an0 = 0.f, an1 = 0.f;
#pragma unroll
            for (int k = 0; k < 32; ++k) {
                float4 h4 = hv[k];
                ar0 = fmaf(wr[k].x, h4.x, ar0); ar1 = fmaf(wr[k].y, h4.y, ar1);
                az0 = fmaf(wz[k].x, h4.x, az0); az1 = fmaf(wz[k].y, h4.y, az1);
                an0 = fmaf(wn[k].x, h4.x, an0); an1 = fmaf(wn[k].y, h4.y, an1);
                ar0 = fmaf(wr[k].z, h4.z, ar0); ar1 = fmaf(wr[k].w, h4.w, ar1);
                az0 = fmaf(wz[k].z, h4.z, az0); az1 = fmaf(wz[k].w, h4.w, az1);
                an0 = fmaf(wn[k].z, h4.z, an0); an1 = fmaf(wn[k].w, h4.w, an1);
            }
            float r = sigm(xdr + (ar0 + ar1) + bhhr);
            float zg = sigm(xdz + (az0 + az1) + bhhz);
            float n = tanh_fast(xdn + r * ((an0 + an1) + bhhn));
            float hnew = fmaf(zg, h_self - n, n);
            h_self = hnew;
            hs[bl][ss][j] = hnew;
            __syncthreads();
        }

        // ---- bulk recon projection for steps s0..s0+31 ----
        // output o = i*5 + d  (i = step-in-tile, d = feature) -> 160 contiguous
        // floats per row; stores perfectly coalesced. Rotated LDS reads
        // (q2 = (q+i)&31) break the stride-128 same-bank pattern.
        float* orow = out + (size_t)b * Tn * Dn + (size_t)s0 * Dn;
#pragma unroll
        for (int rep = 0; rep < 2; ++rep) {
            const int o = j + rep * 128;
            if (o < 160) {
                const int i = o / 5, d = o % 5;
                const float4* wrow = (const float4*)(oW + (size_t)d * Hd);
                const float4* hrow = (const float4*)hs[bl][i];
                float acc = ob[d];
#pragma unroll 4
                for (int q = 0; q < 32; ++q) {
                    const int q2 = (q + i) & 31;
                    float4 h4 = hrow[q2];
                    float4 w4 = wrow[q2];
                    acc = fmaf(w4.x, h4.x, fmaf(w4.y, h4.y, fmaf(w4.z, h4.z, fmaf(w4.w, h4.w, acc))));
                }
                orow[o] = acc;
            }
        }
        __syncthreads();   // protect hs before next tile overwrites slots
    }
}

extern "C" void kernel_launch(void* const* d_in, const int* in_sizes, int n_in,
                              void* d_out, int out_size, void* d_ws, size_t ws_size,
                              hipStream_t stream) {
    const float* x    = (const float*)d_in[0];
    const float* eWih = (const float*)d_in[1];
    const float* eWhh = (const float*)d_in[2];
    const float* ebih = (const float*)d_in[3];
    const float* ebhh = (const float*)d_in[4];
    const float* efcW = (const float*)d_in[5];
    const float* efcb = (const float*)d_in[6];
    const float* dfcW = (const float*)d_in[7];
    const float* dfcb = (const float*)d_in[8];
    const float* dWih = (const float*)d_in[9];
    const float* dWhh = (const float*)d_in[10];
    const float* dbih = (const float*)d_in[11];
    const float* dbhh = (const float*)d_in[12];
    const float* oW   = (const float*)d_in[13];
    const float* ob   = (const float*)d_in[14];
    float* out = (float*)d_out;

    gru_ae_kernel<<<dim3(Bn / 2), dim3(256), 0, stream>>>(
        x, eWih, eWhh, ebih, ebhh, efcW, efcb, dfcW, dfcb,
        dWih, dWhh, dbih, dbhh, oW, ob, out);
}

// Round 4
// 2448.234 us; speedup vs baseline: 1.6046x; 1.6046x over previous
//
#include <hip/hip_runtime.h>

#define Hd 128
#define HF 64
#define Tn 1024
#define Dn 5
#define Ln 16
#define Bn 512

__device__ __forceinline__ float sigm(float x) { return 1.0f / (1.0f + __expf(-x)); }
__device__ __forceinline__ float tanh_fast(float x) { return 1.0f - 2.0f / (1.0f + __expf(2.0f * x)); }

// Persistent GRU autoencoder, K-split-by-2 layout.
// grid = 256 WGs (1/CU), block = 512 threads (8 waves = 2 waves/SIMD).
// Each WG owns batch rows {2*wg, 2*wg+1}. Thread (bl, j, kk): tid = bl*256+j*2+kk
// owns HALF (kk) of W_hh rows {j, 128+j, 256+j} = 3*16 float4 = 192 VGPRs
// (fits the 256 architected-VGPR cap — round-2's 384-reg layout spilled via AGPR
// moves, VGPR_Count=256, VALUBusy 49%). Partner lanes are ADJACENT (tid^1), so
// partial dot sums combine with one __shfl_xor(v,1) per gate — no LDS round-trip,
// no extra barrier. Both lanes redundantly compute the nonlinearity; even lane
// writes h. One barrier per recurrence step.
__global__ __launch_bounds__(512, 2) void gru_ae_kernel(
    const float* __restrict__ x,
    const float* __restrict__ eWih, const float* __restrict__ eWhh,
    const float* __restrict__ ebih, const float* __restrict__ ebhh,
    const float* __restrict__ efcW, const float* __restrict__ efcb,
    const float* __restrict__ dfcW, const float* __restrict__ dfcb,
    const float* __restrict__ dWih, const float* __restrict__ dWhh,
    const float* __restrict__ dbih, const float* __restrict__ dbhh,
    const float* __restrict__ oW, const float* __restrict__ ob,
    float* __restrict__ out)
{
    __shared__ __align__(16) float henc[2][2][Hd];   // ping-pong encoder h per row
    __shared__ __align__(16) float hs[2][32][Hd];    // decoder 32-step h history per row
    __shared__ __align__(16) float hdi[2][Hd];       // decoder input-hidden
    __shared__ float zl[2][Ln];                      // latent z

    const int tid  = threadIdx.x;
    const int bl   = tid >> 8;       // local batch row 0/1
    const int loc  = tid & 255;
    const int j    = loc >> 1;       // hidden index 0..127
    const int kk   = loc & 1;        // K-half 0/1
    const int b    = blockIdx.x * 2 + bl;
    const int koff = kk * HF;

    // ---- encoder W_hh half-rows into registers (192 VGPRs) ----
    float4 wr[16], wz[16], wn[16];
    {
        const float4* p0 = (const float4*)(eWhh + (size_t)j * Hd + koff);
        const float4* p1 = (const float4*)(eWhh + (size_t)(Hd + j) * Hd + koff);
        const float4* p2 = (const float4*)(eWhh + (size_t)(2 * Hd + j) * Hd + koff);
#pragma unroll
        for (int k = 0; k < 16; ++k) { wr[k] = p0[k]; wz[k] = p1[k]; wn[k] = p2[k]; }
    }
    // input-projection rows (D=5) + biases (bias of r/z folded: bih+bhh)
    float wir[5], wiz[5], win[5];
#pragma unroll
    for (int d = 0; d < 5; ++d) {
        wir[d] = eWih[(size_t)j * Dn + d];
        wiz[d] = eWih[(size_t)(Hd + j) * Dn + d];
        win[d] = eWih[(size_t)(2 * Hd + j) * Dn + d];
    }
    float bR = ebih[j] + ebhh[j];
    float bZ = ebih[Hd + j] + ebhh[Hd + j];
    float bihn = ebih[2 * Hd + j];
    float bhhn = ebhh[2 * Hd + j];

    if (loc < Hd) { henc[0][bl][loc] = 0.f; henc[1][bl][loc] = 0.f; }
    __syncthreads();

    float h_self = 0.f;
    int p = 0;
    const float* xrow = x + (size_t)b * Tn * Dn;
    float xc0 = xrow[0], xc1 = xrow[1], xc2 = xrow[2], xc3 = xrow[3], xc4 = xrow[4];

    // ================= encoder: 1024 steps, 1 barrier/step =================
#pragma unroll 1
    for (int t = 0; t < Tn; ++t) {
        const int tn = (t + 1 < Tn) ? (t + 1) : t;
        const float* xq = xrow + tn * Dn;
        float nx0 = xq[0], nx1 = xq[1], nx2 = xq[2], nx3 = xq[3], nx4 = xq[4];

        float xpr = wir[0]*xc0 + wir[1]*xc1 + wir[2]*xc2 + wir[3]*xc3 + wir[4]*xc4;
        float xpz = wiz[0]*xc0 + wiz[1]*xc1 + wiz[2]*xc2 + wiz[3]*xc3 + wiz[4]*xc4;
        float xpn = win[0]*xc0 + win[1]*xc1 + win[2]*xc2 + win[3]*xc3 + win[4]*xc4;

        const float4* hv = (const float4*)&henc[p][bl][koff];
        float ar = 0.f, az = 0.f, an = 0.f;
#pragma unroll
        for (int k = 0; k < 16; ++k) {
            float4 h4 = hv[k];
            ar = fmaf(wr[k].x, h4.x, ar); az = fmaf(wz[k].x, h4.x, az); an = fmaf(wn[k].x, h4.x, an);
            ar = fmaf(wr[k].y, h4.y, ar); az = fmaf(wz[k].y, h4.y, az); an = fmaf(wn[k].y, h4.y, an);
            ar = fmaf(wr[k].z, h4.z, ar); az = fmaf(wz[k].z, h4.z, az); an = fmaf(wn[k].z, h4.z, an);
            ar = fmaf(wr[k].w, h4.w, ar); az = fmaf(wz[k].w, h4.w, az); an = fmaf(wn[k].w, h4.w, an);
        }
        ar += __shfl_xor(ar, 1); az += __shfl_xor(az, 1); an += __shfl_xor(an, 1);
        float r  = sigm(xpr + ar + bR);
        float zg = sigm(xpz + az + bZ);
        float n  = tanh_fast(xpn + bihn + r * (an + bhhn));
        float hnew = fmaf(zg, h_self - n, n);   // (1-z)*n + z*h
        h_self = hnew;
        if (!kk) henc[p ^ 1][bl][j] = hnew;
        xc0 = nx0; xc1 = nx1; xc2 = nx2; xc3 = nx3; xc4 = nx4;
        __syncthreads();
        p ^= 1;
    }

    // ================= latent z =================
    if (loc < Ln) {
        const float4* wp = (const float4*)(efcW + (size_t)loc * Hd);
        const float4* hv = (const float4*)henc[p][bl];
        float acc = efcb[loc];
#pragma unroll
        for (int k = 0; k < 32; ++k) {
            float4 w4 = wp[k], h4 = hv[k];
            acc = fmaf(w4.x, h4.x, fmaf(w4.y, h4.y, fmaf(w4.z, h4.z, fmaf(w4.w, h4.w, acc))));
        }
        out[(size_t)Bn * Tn * Dn + (size_t)b * Ln + loc] = acc;
        zl[bl][loc] = acc;
    }
    __syncthreads();

    // ================= h_dec_in = z @ dec_fc_W.T + dec_fc_b =================
    if (loc < Hd) {
        const float4* wp = (const float4*)(dfcW + (size_t)loc * Ln);
        float acc = dfcb[loc];
#pragma unroll
        for (int l = 0; l < 4; ++l) {
            float4 w4 = wp[l];
            acc = fmaf(w4.x, zl[bl][4*l+0], acc);
            acc = fmaf(w4.y, zl[bl][4*l+1], acc);
            acc = fmaf(w4.z, zl[bl][4*l+2], acc);
            acc = fmaf(w4.w, zl[bl][4*l+3], acc);
        }
        hdi[bl][loc] = acc;
    }
    __syncthreads();

    // ================= xp_dec (constant over decoder steps) =================
    float xdr, xdz, xdn;
    {
        const float4* p0 = (const float4*)(dWih + (size_t)j * Hd + koff);
        const float4* p1 = (const float4*)(dWih + (size_t)(Hd + j) * Hd + koff);
        const float4* p2 = (const float4*)(dWih + (size_t)(2 * Hd + j) * Hd + koff);
#pragma unroll
        for (int k = 0; k < 16; ++k) { wr[k] = p0[k]; wz[k] = p1[k]; wn[k] = p2[k]; }
        const float4* hv = (const float4*)&hdi[bl][koff];
        float a0 = 0.f, a1 = 0.f, a2 = 0.f;
#pragma unroll
        for (int k = 0; k < 16; ++k) {
            float4 h4 = hv[k];
            a0 = fmaf(wr[k].x, h4.x, a0); a1 = fmaf(wz[k].x, h4.x, a1); a2 = fmaf(wn[k].x, h4.x, a2);
            a0 = fmaf(wr[k].y, h4.y, a0); a1 = fmaf(wz[k].y, h4.y, a1); a2 = fmaf(wn[k].y, h4.y, a2);
            a0 = fmaf(wr[k].z, h4.z, a0); a1 = fmaf(wz[k].z, h4.z, a1); a2 = fmaf(wn[k].z, h4.z, a2);
            a0 = fmaf(wr[k].w, h4.w, a0); a1 = fmaf(wz[k].w, h4.w, a1); a2 = fmaf(wn[k].w, h4.w, a2);
        }
        a0 += __shfl_xor(a0, 1); a1 += __shfl_xor(a1, 1); a2 += __shfl_xor(a2, 1);
        xdr = a0 + dbih[j];
        xdz = a1 + dbih[Hd + j];
        xdn = a2 + dbih[2 * Hd + j];
    }

    // ---- decoder W_hh half-rows ----
    {
        const float4* p0 = (const float4*)(dWhh + (size_t)j * Hd + koff);
        const float4* p1 = (const float4*)(dWhh + (size_t)(Hd + j) * Hd + koff);
        const float4* p2 = (const float4*)(dWhh + (size_t)(2 * Hd + j) * Hd + koff);
#pragma unroll
        for (int k = 0; k < 16; ++k) { wr[k] = p0[k]; wz[k] = p1[k]; wn[k] = p2[k]; }
    }
    bR = dbhh[j];
    bZ = dbhh[Hd + j];
    bhhn = dbhh[2 * Hd + j];

    if (loc < Hd) hs[bl][31][loc] = 0.f;   // "previous h" for decoder step 0
    h_self = 0.f;
    __syncthreads();

    // ================= decoder: 1024 steps in 32-step tiles =================
#pragma unroll 1
    for (int s0 = 0; s0 < Tn; s0 += 32) {
#pragma unroll 1
        for (int ss = 0; ss < 32; ++ss) {
            const int ip = (ss + 31) & 31;
            const float4* hv = (const float4*)&hs[bl][ip][koff];
            float ar = 0.f, az = 0.f, an = 0.f;
#pragma unroll
            for (int k = 0; k < 16; ++k) {
                float4 h4 = hv[k];
                ar = fmaf(wr[k].x, h4.x, ar); az = fmaf(wz[k].x, h4.x, az); an = fmaf(wn[k].x, h4.x, an);
                ar = fmaf(wr[k].y, h4.y, ar); az = fmaf(wz[k].y, h4.y, az); an = fmaf(wn[k].y, h4.y, an);
                ar = fmaf(wr[k].z, h4.z, ar); az = fmaf(wz[k].z, h4.z, az); an = fmaf(wn[k].z, h4.z, an);
                ar = fmaf(wr[k].w, h4.w, ar); az = fmaf(wz[k].w, h4.w, az); an = fmaf(wn[k].w, h4.w, an);
            }
            ar += __shfl_xor(ar, 1); az += __shfl_xor(az, 1); an += __shfl_xor(an, 1);
            float r  = sigm(xdr + ar + bR);
            float zg = sigm(xdz + az + bZ);
            float n  = tanh_fast(xdn + r * (an + bhhn));
            float hnew = fmaf(zg, h_self - n, n);
            h_self = hnew;
            if (!kk) hs[bl][ss][j] = hnew;
            __syncthreads();
        }

        // ---- bulk recon projection for steps s0..s0+31 (coalesced stores) ----
        if (tid < 320) {
            const int rowp = tid / 160, o = tid % 160;
            const int i = o / 5, d = o % 5;
            const float4* wrow = (const float4*)(oW + (size_t)d * Hd);
            const float4* hrow = (const float4*)hs[rowp][i];
            float ac0 = ob[d], ac1 = 0.f;
#pragma unroll
            for (int q = 0; q < 32; q += 2) {
                const int qa = (q + i) & 31, qb = (q + 1 + i) & 31;
                float4 ha = hrow[qa], wa = wrow[qa];
                float4 hb = hrow[qb], wb = wrow[qb];
                ac0 = fmaf(wa.x, ha.x, fmaf(wa.y, ha.y, fmaf(wa.z, ha.z, fmaf(wa.w, ha.w, ac0))));
                ac1 = fmaf(wb.x, hb.x, fmaf(wb.y, hb.y, fmaf(wb.z, hb.z, fmaf(wb.w, hb.w, ac1))));
            }
            out[((size_t)(blockIdx.x * 2 + rowp) * Tn + s0 + i) * Dn + d] = ac0 + ac1;
        }
        __syncthreads();   // protect hs before next tile overwrites slots
    }
}

extern "C" void kernel_launch(void* const* d_in, const int* in_sizes, int n_in,
                              void* d_out, int out_size, void* d_ws, size_t ws_size,
                              hipStream_t stream) {
    const float* x    = (const float*)d_in[0];
    const float* eWih = (const float*)d_in[1];
    const float* eWhh = (const float*)d_in[2];
    const float* ebih = (const float*)d_in[3];
    const float* ebhh = (const float*)d_in[4];
    const float* efcW = (const float*)d_in[5];
    const float* efcb = (const float*)d_in[6];
    const float* dfcW = (const float*)d_in[7];
    const float* dfcb = (const float*)d_in[8];
    const float* dWih = (const float*)d_in[9];
    const float* dWhh = (const float*)d_in[10];
    const float* dbih = (const float*)d_in[11];
    const float* dbhh = (const float*)d_in[12];
    const float* oW   = (const float*)d_in[13];
    const float* ob   = (const float*)d_in[14];
    float* out = (float*)d_out;

    gru_ae_kernel<<<dim3(Bn / 2), dim3(512), 0, stream>>>(
        x, eWih, eWhh, ebih, ebhh, efcW, efcb, dfcW, dfcb,
        dWih, dWhh, dbih, dbhh, oW, ob, out);
}